// Round 1
// 711.766 us; speedup vs baseline: 1.1113x; 1.1113x over previous
//
#include <hip/hip_runtime.h>

typedef unsigned short u16;
typedef unsigned int u32;
typedef __attribute__((ext_vector_type(8))) short short8;
typedef __attribute__((ext_vector_type(4))) float f32x4;

#define M_ROWS 32768

__device__ __forceinline__ float bf2f(u16 u) {
  u32 x = ((u32)u) << 16;
  return __builtin_bit_cast(float, x);
}
__device__ __forceinline__ u16 f2bf(float f) {
  u32 x = __builtin_bit_cast(u32, f);
  x += 0x7fffu + ((x >> 16) & 1u);
  return (u16)(x >> 16);
}
// load 8 fp32 from p, RNE-round to one short8
__device__ __forceinline__ short8 ld8f(const float* p) {
  f32x4 x0 = *(const f32x4*)p;
  f32x4 x1 = *(const f32x4*)(p + 4);
  short8 s;
#pragma unroll
  for (int i = 0; i < 4; ++i) { s[i] = (short)f2bf(x0[i]); s[4 + i] = (short)f2bf(x1[i]); }
  return s;
}

// async global->LDS, 16B per lane, LDS dest = wave-uniform base + lane*16
__device__ __forceinline__ void lds16(u16* l, const u16* g) {
  __builtin_amdgcn_global_load_lds(
      (const __attribute__((address_space(1))) void*)g,
      (__attribute__((address_space(3))) void*)l, 16, 0, 0);
}

// ---------------- input pack: fp32 -> bf16 (+ ctx gather) -----------------------
__global__ __launch_bounds__(256) void pack(
    const float* gvec, const float* xnode, const float* znode,
    const float* src, const float* atom1h, const int* bidx,
    u16* gvecB, u16* xnodeB, u16* znodeB, u16* ctxB, u16* a1hB) {
  int id = blockIdx.x * 256 + threadIdx.x;  // one short8 chunk each
  const int NG = M_ROWS * 512 / 8;          // 2097152
  if (id < NG) { ((short8*)gvecB)[id] = ld8f(gvec + (size_t)id * 8); return; }
  id -= NG;
  if (id < NG) { ((short8*)xnodeB)[id] = ld8f(xnode + (size_t)id * 8); return; }
  id -= NG;
  if (id < NG) { ((short8*)znodeB)[id] = ld8f(znode + (size_t)id * 8); return; }
  id -= NG;
  const int NC = M_ROWS * 128 / 8;          // 524288
  if (id < NC) {
    const int m = id >> 4, c8 = (id & 15) * 8;
    ((short8*)ctxB)[id] = ld8f(src + (size_t)bidx[m] * 128 + c8);
    return;
  }
  id -= NC;
  const int NA = M_ROWS * 64 / 8;           // 262144
  if (id < NA) { ((short8*)a1hB)[id] = ld8f(atom1h + (size_t)id * 8); return; }
}

// ---------------- generic 128x128 GEMM (G1: wbond w/ rank-4 tail, G2: rbond) ----
struct SegB { const u16* ptr; int ld; int kstart; };
struct GArgs {
  SegB seg[2];
  int nseg;
  const u16* bt;       // B^T [N][K] bf16
  const float* biasf;  // [N] fp32
  u16* out;            // [M][N] relu'd bf16
  int K;
  int N;
  const float* tail_w; // fp32 wbond_w rows 512..515 (ld 512) or null
  const float* tail_x; // fp32 bond_onehot [M][4] or null
};

__global__ __launch_bounds__(256) void gemm_ms(GArgs a) {
  __shared__ u16 As[4096];
  __shared__ u16 Bs[4096];
  const int tid = threadIdx.x;
  const int bm = blockIdx.x, bn = blockIdx.y;
  const int wave = tid >> 6, lane = tid & 63;
  const int wm = wave >> 1, wn = wave & 1;
  const int lm = lane & 15, lq = lane >> 4;
  const int ch0 = wave * 2;                  // this wave's two 16-row chunks
  const int srow = ch0 * 16 + (lane >> 2);   // staging row (chunk0)
  const int scol = (lane & 3) * 8;           // staging col (elements)
  const int gmA = bm * 128 + srow;
  const int gnB = bn * 128 + srow;
  u16* lA0 = As + ch0 * 512; u16* lA1 = lA0 + 512;
  u16* lB0 = Bs + ch0 * 512; u16* lB1 = lB0 + 512;
  const int K = a.K;
  const u16* pb = a.bt + (size_t)gnB * K + scol;

  f32x4 acc[4][4] = {};
  for (int kb = 0; kb < K; kb += 32) {
    const SegB* s = &a.seg[0];
    if (a.nseg > 1 && kb >= a.seg[1].kstart) s = &a.seg[1];
    const u16* pa = s->ptr + (size_t)gmA * s->ld + (kb - s->kstart) + scol;
    lds16(lB0, pb + kb);
    lds16(lB1, pb + kb + (size_t)16 * K);
    lds16(lA0, pa);
    lds16(lA1, pa + (size_t)16 * s->ld);
    __syncthreads();

    short8 af[4], bfr[4];
#pragma unroll
    for (int i = 0; i < 4; ++i)
      af[i] = *(const short8*)&As[(wm * 64 + i * 16 + lm) * 32 + lq * 8];
#pragma unroll
    for (int j = 0; j < 4; ++j)
      bfr[j] = *(const short8*)&Bs[(wn * 64 + j * 16 + lm) * 32 + lq * 8];
#pragma unroll
    for (int i = 0; i < 4; ++i)
#pragma unroll
      for (int j = 0; j < 4; ++j)
        acc[i][j] = __builtin_amdgcn_mfma_f32_16x16x32_bf16(af[i], bfr[j], acc[i][j], 0, 0, 0);
    __syncthreads();
  }

  const int gc0 = bn * 128 + wn * 64 + lm;
  float biasv[4], tw[4][4];
#pragma unroll
  for (int j = 0; j < 4; ++j) {
    const int gc = gc0 + j * 16;
    biasv[j] = a.biasf[gc];
    if (a.tail_w) {
#pragma unroll
      for (int k = 0; k < 4; ++k) tw[j][k] = a.tail_w[k * 512 + gc];
    }
  }
#pragma unroll
  for (int i = 0; i < 4; ++i) {
#pragma unroll
    for (int r = 0; r < 4; ++r) {
      const int gr = bm * 128 + wm * 64 + i * 16 + lq * 4 + r;
      float tx0 = 0.f, tx1 = 0.f, tx2 = 0.f, tx3 = 0.f;
      if (a.tail_w) {
        tx0 = a.tail_x[gr * 4 + 0];
        tx1 = a.tail_x[gr * 4 + 1];
        tx2 = a.tail_x[gr * 4 + 2];
        tx3 = a.tail_x[gr * 4 + 3];
      }
#pragma unroll
      for (int j = 0; j < 4; ++j) {
        float v = acc[i][j][r] + biasv[j];
        if (a.tail_w) v += tx0 * tw[j][0] + tx1 * tw[j][1] + tx2 * tw[j][2] + tx3 * tw[j][3];
        v = v > 0.f ? v : 0.f;
        a.out[(size_t)gr * a.N + gc0 + j * 16] = f2bf(v);
      }
    }
  }
}

// ---------------- topo+atom: layer1 GEMM (K=1152) with fused layer-2 heads ------
struct TAArgs {
  const u16* gvecB; const u16* xnodeB; const u16* ctxB;
  const u16* bt;      // TAT [1024][1152] bf16
  const float* tb1;   // topo_b1 [512] fp32
  const float* ab1;   // atom_b1 [512] fp32
  const float* tw2;   // topo_w2 [512] fp32
  const float* tb2;   // topo_b2 [1] fp32
  const u16* aw2t;    // AT2 [64][512] bf16
  const float* ab2;   // atom_b2 [64] fp32
  float* out;         // d_out fp32 [M][69]
};

__global__ __launch_bounds__(256) void gemm_ta_heads(TAArgs a) {
  __shared__ u16 As[4096];
  __shared__ u16 Bs[4096];
  __shared__ u16 hbuf[128 * 136];
  const int tid = threadIdx.x;
  const int bm = blockIdx.x, half = blockIdx.y; // 0=topo cols, 1=atom cols
  const int wave = tid >> 6, lane = tid & 63;
  const int wm = wave >> 1, wn = wave & 1;
  const int lm = lane & 15, lq = lane >> 4;
  const int ch0 = wave * 2;
  const int srow = ch0 * 16 + (lane >> 2);
  const int scol = (lane & 3) * 8;
  const int gmA = bm * 128 + srow;
  u16* lA0 = As + ch0 * 512; u16* lA1 = lA0 + 512;
  u16* lB0 = Bs + ch0 * 512; u16* lB1 = lB0 + 512;

  float topo_acc = 0.f;
  f32x4 acc2[2][4] = {};

  for (int t = 0; t < 4; ++t) {
    const int colbase = half * 512 + t * 128;
    const u16* pb = a.bt + (size_t)(colbase + srow) * 1152 + scol;
    f32x4 acc[4][4] = {};
    for (int kb = 0; kb < 1152; kb += 32) {
      const u16* p; int ks, ld;
      if (kb < 512)       { p = a.gvecB;  ks = 0;    ld = 512; }
      else if (kb < 1024) { p = a.xnodeB; ks = 512;  ld = 512; }
      else                { p = a.ctxB;   ks = 1024; ld = 128; }
      const u16* pa = p + (size_t)gmA * ld + (kb - ks) + scol;
      lds16(lB0, pb + kb);
      lds16(lB1, pb + kb + (size_t)16 * 1152);
      lds16(lA0, pa);
      lds16(lA1, pa + (size_t)16 * ld);
      __syncthreads();
      short8 af[4], bfr[4];
#pragma unroll
      for (int i = 0; i < 4; ++i)
        af[i] = *(const short8*)&As[(wm * 64 + i * 16 + lm) * 32 + lq * 8];
#pragma unroll
      for (int j = 0; j < 4; ++j)
        bfr[j] = *(const short8*)&Bs[(wn * 64 + j * 16 + lm) * 32 + lq * 8];
#pragma unroll
      for (int i = 0; i < 4; ++i)
#pragma unroll
        for (int j = 0; j < 4; ++j)
          acc[i][j] = __builtin_amdgcn_mfma_f32_16x16x32_bf16(af[i], bfr[j], acc[i][j], 0, 0, 0);
      __syncthreads();
    }
    // h = relu(acc + b1) -> hbuf
    const float* bsrc = half ? a.ab1 : a.tb1;
    const int c0 = wn * 64 + lm;
    float bv[4];
#pragma unroll
    for (int j = 0; j < 4; ++j) bv[j] = bsrc[t * 128 + c0 + j * 16];
#pragma unroll
    for (int i = 0; i < 4; ++i) {
#pragma unroll
      for (int r = 0; r < 4; ++r) {
        const int rl = wm * 64 + i * 16 + lq * 4 + r;
#pragma unroll
        for (int j = 0; j < 4; ++j) {
          float v = acc[i][j][r] + bv[j];
          v = v > 0.f ? v : 0.f;
          hbuf[rl * 136 + c0 + j * 16] = f2bf(v);
        }
      }
    }
    __syncthreads();

    if (half == 0) {
      const int srw = tid >> 1, sh = tid & 1;
      const u16* hrow = &hbuf[srw * 136 + sh * 64];
      float s = 0.f;
      for (int cc = 0; cc < 64; ++cc)
        s += bf2f(hrow[cc]) * a.tw2[t * 128 + sh * 64 + cc];
      topo_acc += s;
    } else {
#pragma unroll
      for (int ks2 = 0; ks2 < 4; ++ks2) {
#pragma unroll
        for (int i2 = 0; i2 < 2; ++i2) {
          const short8 af2 = *(const short8*)&hbuf[(wave * 32 + i2 * 16 + lm) * 136 + ks2 * 32 + lq * 8];
#pragma unroll
          for (int j2 = 0; j2 < 4; ++j2) {
            const short8 bf2v = *(const short8*)&a.aw2t[(size_t)(j2 * 16 + lm) * 512 + t * 128 + ks2 * 32 + lq * 8];
            acc2[i2][j2] = __builtin_amdgcn_mfma_f32_16x16x32_bf16(af2, bf2v, acc2[i2][j2], 0, 0, 0);
          }
        }
      }
    }
    __syncthreads();
  }

  if (half == 0) {
    float s = topo_acc + __shfl_xor(topo_acc, 1);
    if ((tid & 1) == 0) {
      const int m = bm * 128 + (tid >> 1);
      a.out[(size_t)m * 69] = s + a.tb2[0];
    }
  } else {
#pragma unroll
    for (int i2 = 0; i2 < 2; ++i2)
#pragma unroll
      for (int j2 = 0; j2 < 4; ++j2)
#pragma unroll
        for (int r = 0; r < 4; ++r) {
          const int m = bm * 128 + wave * 32 + i2 * 16 + lq * 4 + r;
          const int o = j2 * 16 + lm;
          a.out[(size_t)m * 69 + 1 + o] = acc2[i2][j2][r] + a.ab2[o];
        }
  }
}

// ---------------- bond: layer1 GEMM (K=1664) with per-tile head partials --------
struct BDArgs {
  const u16* gvecB; const u16* cur; const u16* znodeB; const u16* ctxB;
  const u16* bt;     // BdT [512][1664] bf16
  const float* b1;   // bond_b1 [512] fp32
  const float* bw2;  // bond_w2 [512][4] fp32
  float* p4;         // [4][M][4] fp32 partials
};

__global__ __launch_bounds__(256) void gemm_bond(BDArgs a) {
  __shared__ u16 As[4096];
  __shared__ u16 Bs[4096];
  __shared__ u16 hbuf[128 * 136];
  const int tid = threadIdx.x;
  const int bm = blockIdx.x, t = blockIdx.y;
  const int wave = tid >> 6, lane = tid & 63;
  const int wm = wave >> 1, wn = wave & 1;
  const int lm = lane & 15, lq = lane >> 4;
  const int ch0 = wave * 2;
  const int srow = ch0 * 16 + (lane >> 2);
  const int scol = (lane & 3) * 8;
  const int gmA = bm * 128 + srow;
  const int colbase = t * 128;
  u16* lA0 = As + ch0 * 512; u16* lA1 = lA0 + 512;
  u16* lB0 = Bs + ch0 * 512; u16* lB1 = lB0 + 512;
  const u16* pb = a.bt + (size_t)(colbase + srow) * 1664 + scol;

  f32x4 acc[4][4] = {};
  for (int kb = 0; kb < 1664; kb += 32) {
    const u16* p; int ks, ld;
    if (kb < 512)       { p = a.gvecB;  ks = 0;    ld = 512; }
    else if (kb < 1024) { p = a.cur;    ks = 512;  ld = 512; }
    else if (kb < 1536) { p = a.znodeB; ks = 1024; ld = 512; }
    else                { p = a.ctxB;   ks = 1536; ld = 128; }
    const u16* pa = p + (size_t)gmA * ld + (kb - ks) + scol;
    lds16(lB0, pb + kb);
    lds16(lB1, pb + kb + (size_t)16 * 1664);
    lds16(lA0, pa);
    lds16(lA1, pa + (size_t)16 * ld);
    __syncthreads();
    short8 af[4], bfr[4];
#pragma unroll
    for (int i = 0; i < 4; ++i)
      af[i] = *(const short8*)&As[(wm * 64 + i * 16 + lm) * 32 + lq * 8];
#pragma unroll
    for (int j = 0; j < 4; ++j)
      bfr[j] = *(const short8*)&Bs[(wn * 64 + j * 16 + lm) * 32 + lq * 8];
#pragma unroll
    for (int i = 0; i < 4; ++i)
#pragma unroll
      for (int j = 0; j < 4; ++j)
        acc[i][j] = __builtin_amdgcn_mfma_f32_16x16x32_bf16(af[i], bfr[j], acc[i][j], 0, 0, 0);
    __syncthreads();
  }

  const int c0 = wn * 64 + lm;
  float bv[4];
#pragma unroll
  for (int j = 0; j < 4; ++j) bv[j] = a.b1[colbase + c0 + j * 16];
#pragma unroll
  for (int i = 0; i < 4; ++i) {
#pragma unroll
    for (int r = 0; r < 4; ++r) {
      const int rl = wm * 64 + i * 16 + lq * 4 + r;
#pragma unroll
      for (int j = 0; j < 4; ++j) {
        float v = acc[i][j][r] + bv[j];
        v = v > 0.f ? v : 0.f;
        hbuf[rl * 136 + c0 + j * 16] = f2bf(v);
      }
    }
  }
  __syncthreads();

  const int srw = tid >> 1, sh = tid & 1;
  const u16* hrow = &hbuf[srw * 136 + sh * 64];
  float s[4] = {0.f, 0.f, 0.f, 0.f};
  for (int cc = 0; cc < 64; ++cc) {
    const float h = bf2f(hrow[cc]);
#pragma unroll
    for (int o = 0; o < 4; ++o)
      s[o] += h * a.bw2[(colbase + sh * 64 + cc) * 4 + o];
  }
#pragma unroll
  for (int o = 0; o < 4; ++o) s[o] += __shfl_xor(s[o], 1);
  if ((tid & 1) == 0) {
    const int m = bm * 128 + srw;
#pragma unroll
    for (int o = 0; o < 4; ++o)
      a.p4[((size_t)t * M_ROWS + m) * 4 + o] = s[o];
  }
}

__global__ __launch_bounds__(256) void bond_fin(const float* p4, const float* bb2, float* out) {
  const int id = blockIdx.x * 256 + threadIdx.x;
  if (id >= M_ROWS * 4) return;
  const int m = id >> 2, o = id & 3;
  float v = bb2[o];
#pragma unroll
  for (int t = 0; t < 4; ++t) v += p4[((size_t)t * M_ROWS + m) * 4 + o];
  out[(size_t)m * 69 + 65 + o] = v;
}

// ---------------- weight transpose + fp32->bf16 conversion ----------------------
__global__ __launch_bounds__(256) void prep(
    const float* topo_w1, const float* atom_w1, const float* bond_w1,
    const float* rbond_w, const float* wbond_w, const float* atom_w2,
    u16* WbT, u16* RbT, u16* TAT, u16* BdT, u16* AT2) {
  int id = blockIdx.x * 256 + threadIdx.x;
  if (id < 512 * 512) { int n = id >> 9, k = id & 511; WbT[id] = f2bf(wbond_w[k * 512 + n]); return; }
  id -= 512 * 512;
  if (id < 512 * 576) { int n = id / 576, k = id % 576; RbT[id] = f2bf(rbond_w[k * 512 + n]); return; }
  id -= 512 * 576;
  if (id < 1024 * 1152) {
    int n = id / 1152, k = id % 1152;
    TAT[id] = f2bf((n < 512) ? topo_w1[k * 512 + n] : atom_w1[k * 512 + (n - 512)]);
    return;
  }
  id -= 1024 * 1152;
  if (id < 512 * 1664) { int n = id / 1664, k = id % 1664; BdT[id] = f2bf(bond_w1[k * 512 + n]); return; }
  id -= 512 * 1664;
  if (id < 64 * 512) { int n = id >> 9, k = id & 511; AT2[id] = f2bf(atom_w2[k * 64 + n]); return; }
}

extern "C" void kernel_launch(void* const* d_in, const int* in_sizes, int n_in,
                              void* d_out, int out_size, void* d_ws, size_t ws_size,
                              hipStream_t stream) {
  const float* src     = (const float*)d_in[0];
  const float* gvec    = (const float*)d_in[1];
  const float* xnode   = (const float*)d_in[2];
  const float* znode   = (const float*)d_in[3];
  const float* atom1h  = (const float*)d_in[4];
  const float* bond1h  = (const float*)d_in[5];
  const float* topo_w1 = (const float*)d_in[6];
  const float* topo_b1 = (const float*)d_in[7];
  const float* topo_w2 = (const float*)d_in[8];
  const float* topo_b2 = (const float*)d_in[9];
  const float* atom_w1 = (const float*)d_in[10];
  const float* atom_b1 = (const float*)d_in[11];
  const float* atom_w2 = (const float*)d_in[12];
  const float* atom_b2 = (const float*)d_in[13];
  const float* bond_w1 = (const float*)d_in[14];
  const float* bond_b1 = (const float*)d_in[15];
  const float* bond_w2 = (const float*)d_in[16];
  const float* bond_b2 = (const float*)d_in[17];
  const float* rbond_w = (const float*)d_in[18];
  const float* rbond_b = (const float*)d_in[19];
  const float* wbond_w = (const float*)d_in[20];
  const float* wbond_b = (const float*)d_in[21];
  const int* bidx      = (const int*)d_in[22];

  char* ws = (char*)d_ws;
  u16*  WbT  = (u16*)(ws + 0);          // 512x512 bf16
  u16*  RbT  = (u16*)(ws + 524288);     // 512x576
  u16*  TAT  = (u16*)(ws + 1114112);    // 1024x1152
  u16*  BdT  = (u16*)(ws + 3473408);    // 512x1664
  u16*  AT2  = (u16*)(ws + 5177344);    // 64x512
  float* P4  = (float*)(ws + 5242880);  // 4 x M x 4 fp32     (end 7340032)
  u16*  hist = (u16*)(ws + 7340032);    // M x 512 bf16 -- ALIASES xnodeB (dead after ta)
  u16*  xnodeB = (u16*)(ws + 7340032);  // M x 512 bf16
  u16*  cur  = (u16*)(ws + 40894464);   // M x 512 bf16
  u16*  gvecB  = (u16*)(ws + 74448896); // M x 512 bf16
  u16*  znodeB = (u16*)(ws + 108003328);// M x 512 bf16
  u16*  ctxB   = (u16*)(ws + 141557760);// M x 128 bf16 (gathered via bidx)
  u16*  a1hB   = (u16*)(ws + 149946368);// M x 64 bf16        (end 154140672)

  prep<<<dim3(10240), dim3(256), 0, stream>>>(
      topo_w1, atom_w1, bond_w1, rbond_w, wbond_w, atom_w2,
      WbT, RbT, TAT, BdT, AT2);

  pack<<<dim3(27648), dim3(256), 0, stream>>>(
      gvec, xnode, znode, src, atom1h, bidx,
      gvecB, xnodeB, znodeB, ctxB, a1hB);

  // ta first: xnodeB is dead after this, so hist may alias it.
  TAArgs ta = {gvecB, xnodeB, ctxB, TAT, topo_b1, atom_b1,
               topo_w2, topo_b2, AT2, atom_b2, (float*)d_out};
  gemm_ta_heads<<<dim3(256, 2), dim3(256), 0, stream>>>(ta);

  GArgs g1 = {};
  g1.seg[0] = {znodeB, 512, 0}; g1.nseg = 1;
  g1.bt = WbT; g1.biasf = wbond_b; g1.out = hist; g1.K = 512; g1.N = 512;
  g1.tail_w = wbond_w + 512 * 512; g1.tail_x = bond1h;
  gemm_ms<<<dim3(256, 4), dim3(256), 0, stream>>>(g1);

  GArgs g2 = {};
  g2.seg[0] = {hist, 512, 0}; g2.seg[1] = {a1hB, 64, 512}; g2.nseg = 2;
  g2.bt = RbT; g2.biasf = rbond_b; g2.out = cur; g2.K = 576; g2.N = 512;
  gemm_ms<<<dim3(256, 4), dim3(256), 0, stream>>>(g2);

  BDArgs bd = {gvecB, cur, znodeB, ctxB, BdT, bond_b1, bond_w2, P4};
  gemm_bond<<<dim3(256, 4), dim3(256), 0, stream>>>(bd);

  bond_fin<<<dim3(512), dim3(256), 0, stream>>>(P4, bond_b2, (float*)d_out);
}

// Round 2
// 670.675 us; speedup vs baseline: 1.1794x; 1.0613x over previous
//
#include <hip/hip_runtime.h>

typedef unsigned short u16;
typedef unsigned int u32;
typedef __attribute__((ext_vector_type(8))) short short8;
typedef __attribute__((ext_vector_type(4))) float f32x4;

#define M_ROWS 32768

__device__ __forceinline__ float bf2f(u16 u) {
  u32 x = ((u32)u) << 16;
  return __builtin_bit_cast(float, x);
}
__device__ __forceinline__ u16 f2bf(float f) {
  u32 x = __builtin_bit_cast(u32, f);
  x += 0x7fffu + ((x >> 16) & 1u);
  return (u16)(x >> 16);
}
// load 8 fp32 from p, RNE-round to one short8
__device__ __forceinline__ short8 ld8f(const float* p) {
  f32x4 x0 = *(const f32x4*)p;
  f32x4 x1 = *(const f32x4*)(p + 4);
  short8 s;
#pragma unroll
  for (int i = 0; i < 4; ++i) { s[i] = (short)f2bf(x0[i]); s[4 + i] = (short)f2bf(x1[i]); }
  return s;
}

// async global->LDS, 16B per lane, LDS dest = wave-uniform base + lane*16
__device__ __forceinline__ void lds16(u16* l, const u16* g) {
  __builtin_amdgcn_global_load_lds(
      (const __attribute__((address_space(1))) void*)g,
      (__attribute__((address_space(3))) void*)l, 16, 0, 0);
}

// ---------------- input pack: fp32 -> bf16 (+ ctx gather) -----------------------
__global__ __launch_bounds__(256) void pack(
    const float* gvec, const float* xnode, const float* znode,
    const float* src, const float* atom1h, const int* bidx,
    u16* gvecB, u16* xnodeB, u16* znodeB, u16* ctxB, u16* a1hB) {
  int id = blockIdx.x * 256 + threadIdx.x;  // one short8 chunk each
  const int NG = M_ROWS * 512 / 8;          // 2097152
  if (id < NG) { ((short8*)gvecB)[id] = ld8f(gvec + (size_t)id * 8); return; }
  id -= NG;
  if (id < NG) { ((short8*)xnodeB)[id] = ld8f(xnode + (size_t)id * 8); return; }
  id -= NG;
  if (id < NG) { ((short8*)znodeB)[id] = ld8f(znode + (size_t)id * 8); return; }
  id -= NG;
  const int NC = M_ROWS * 128 / 8;          // 524288
  if (id < NC) {
    const int m = id >> 4, c8 = (id & 15) * 8;
    ((short8*)ctxB)[id] = ld8f(src + (size_t)bidx[m] * 128 + c8);
    return;
  }
  id -= NC;
  const int NA = M_ROWS * 64 / 8;           // 262144
  if (id < NA) { ((short8*)a1hB)[id] = ld8f(atom1h + (size_t)id * 8); return; }
}

// ---------------- unified layer-1 GEMM: 128x128 tile, up to 4 A-segments --------
// out = relu(A @ B^T + bias [+ tail rank-4])  in bf16
struct SegB { const u16* ptr; int ld; int kstart; };
struct GArgs {
  SegB seg[4];
  int nseg;
  const u16* bt;       // B^T [N][K] bf16
  const float* biasf;  // [N] fp32
  u16* out;            // [M][N] relu'd bf16
  int K;
  int N;
  const float* tail_w; // fp32 wbond_w rows 512..515 (ld 512) or null
  const float* tail_x; // fp32 bond_onehot [M][4] or null
};

__global__ __launch_bounds__(256) void gemm_ms(GArgs a) {
  __shared__ u16 As[4096];
  __shared__ u16 Bs[4096];
  const int tid = threadIdx.x;
  const int bn = blockIdx.x, bm = blockIdx.y;  // x = n-tile (fast) -> A reuse
  const int wave = tid >> 6, lane = tid & 63;
  const int wm = wave >> 1, wn = wave & 1;
  const int lm = lane & 15, lq = lane >> 4;
  const int ch0 = wave * 2;                  // this wave's two 16-row chunks
  const int srow = ch0 * 16 + (lane >> 2);   // staging row (chunk0)
  const int scol = (lane & 3) * 8;           // staging col (elements)
  const int gmA = bm * 128 + srow;
  const int gnB = bn * 128 + srow;
  u16* lA0 = As + ch0 * 512; u16* lA1 = lA0 + 512;
  u16* lB0 = Bs + ch0 * 512; u16* lB1 = lB0 + 512;
  const int K = a.K;
  const u16* pb = a.bt + (size_t)gnB * K + scol;

  f32x4 acc[4][4] = {};
  for (int kb = 0; kb < K; kb += 32) {
    int si = a.nseg - 1;
    while (si > 0 && kb < a.seg[si].kstart) --si;
    const u16* sp = a.seg[si].ptr;
    const int sld = a.seg[si].ld;
    const u16* pa = sp + (size_t)gmA * sld + (kb - a.seg[si].kstart) + scol;
    lds16(lB0, pb + kb);
    lds16(lB1, pb + kb + (size_t)16 * K);
    lds16(lA0, pa);
    lds16(lA1, pa + (size_t)16 * sld);
    __syncthreads();

    short8 af[4], bfr[4];
#pragma unroll
    for (int i = 0; i < 4; ++i)
      af[i] = *(const short8*)&As[(wm * 64 + i * 16 + lm) * 32 + lq * 8];
#pragma unroll
    for (int j = 0; j < 4; ++j)
      bfr[j] = *(const short8*)&Bs[(wn * 64 + j * 16 + lm) * 32 + lq * 8];
#pragma unroll
    for (int i = 0; i < 4; ++i)
#pragma unroll
      for (int j = 0; j < 4; ++j)
        acc[i][j] = __builtin_amdgcn_mfma_f32_16x16x32_bf16(af[i], bfr[j], acc[i][j], 0, 0, 0);
    __syncthreads();
  }

  const int gc0 = bn * 128 + wn * 64 + lm;
  float biasv[4], tw[4][4];
#pragma unroll
  for (int j = 0; j < 4; ++j) {
    const int gc = gc0 + j * 16;
    biasv[j] = a.biasf[gc];
    if (a.tail_w) {
#pragma unroll
      for (int k = 0; k < 4; ++k) tw[j][k] = a.tail_w[k * 512 + gc];
    }
  }
#pragma unroll
  for (int i = 0; i < 4; ++i) {
#pragma unroll
    for (int r = 0; r < 4; ++r) {
      const int gr = bm * 128 + wm * 64 + i * 16 + lq * 4 + r;
      float tx0 = 0.f, tx1 = 0.f, tx2 = 0.f, tx3 = 0.f;
      if (a.tail_w) {
        tx0 = a.tail_x[gr * 4 + 0];
        tx1 = a.tail_x[gr * 4 + 1];
        tx2 = a.tail_x[gr * 4 + 2];
        tx3 = a.tail_x[gr * 4 + 3];
      }
#pragma unroll
      for (int j = 0; j < 4; ++j) {
        float v = acc[i][j][r] + biasv[j];
        if (a.tail_w) v += tx0 * tw[j][0] + tx1 * tw[j][1] + tx2 * tw[j][2] + tx3 * tw[j][3];
        v = v > 0.f ? v : 0.f;
        a.out[(size_t)gr * a.N + gc0 + j * 16] = f2bf(v);
      }
    }
  }
}

// ---------------- topo + atom heads from materialized h1 [M][1024] --------------
struct THArgs {
  const u16* h1;      // [M][1024] relu'd bf16 (cols 0..511 topo, 512..1023 atom)
  const float* tw2;   // topo_w2 [512] fp32
  const float* tb2;   // topo_b2 [1]
  const u16* aw2t;    // AT2 [64][512] bf16
  const float* ab2;   // atom_b2 [64]
  float* out;         // [M][69] fp32
};

__global__ __launch_bounds__(256) void ta_heads(THArgs a) {
  __shared__ u16 hbuf[128 * 136];
  const int tid = threadIdx.x;
  const int half = blockIdx.x, bm = blockIdx.y;  // half: 0=topo, 1=atom
  const int wave = tid >> 6, lane = tid & 63;
  const int lm = lane & 15, lq = lane >> 4;

  float topo_acc = 0.f;
  f32x4 acc2[2][4] = {};

  for (int t = 0; t < 4; ++t) {
    // stage h1[bm*128 ..][half*512 + t*128 ..] -> hbuf[128][136] (padded)
#pragma unroll
    for (int it = 0; it < 8; ++it) {
      const int id = it * 256 + tid;
      const int row = id >> 4, c8 = (id & 15) * 8;
      short8 v = *(const short8*)(a.h1 + (size_t)(bm * 128 + row) * 1024 + half * 512 + t * 128 + c8);
      *(short8*)&hbuf[row * 136 + c8] = v;
    }
    __syncthreads();

    if (half == 0) {
      const int srw = tid >> 1, sh = tid & 1;
      const u16* hrow = &hbuf[srw * 136 + sh * 64];
      float s = 0.f;
      for (int cc = 0; cc < 64; ++cc)
        s += bf2f(hrow[cc]) * a.tw2[t * 128 + sh * 64 + cc];
      topo_acc += s;
    } else {
#pragma unroll
      for (int ks2 = 0; ks2 < 4; ++ks2) {
#pragma unroll
        for (int i2 = 0; i2 < 2; ++i2) {
          const short8 af2 = *(const short8*)&hbuf[(wave * 32 + i2 * 16 + lm) * 136 + ks2 * 32 + lq * 8];
#pragma unroll
          for (int j2 = 0; j2 < 4; ++j2) {
            const short8 bf2v = *(const short8*)&a.aw2t[(size_t)(j2 * 16 + lm) * 512 + t * 128 + ks2 * 32 + lq * 8];
            acc2[i2][j2] = __builtin_amdgcn_mfma_f32_16x16x32_bf16(af2, bf2v, acc2[i2][j2], 0, 0, 0);
          }
        }
      }
    }
    __syncthreads();
  }

  if (half == 0) {
    float s = topo_acc + __shfl_xor(topo_acc, 1);
    if ((tid & 1) == 0) {
      const int m = bm * 128 + (tid >> 1);
      a.out[(size_t)m * 69] = s + a.tb2[0];
    }
  } else {
#pragma unroll
    for (int i2 = 0; i2 < 2; ++i2)
#pragma unroll
      for (int j2 = 0; j2 < 4; ++j2)
#pragma unroll
        for (int r = 0; r < 4; ++r) {
          const int m = bm * 128 + wave * 32 + i2 * 16 + lq * 4 + r;
          const int o = j2 * 16 + lm;
          a.out[(size_t)m * 69 + 1 + o] = acc2[i2][j2][r] + a.ab2[o];
        }
  }
}

// ---------------- bond head from materialized hb [M][512] -----------------------
__global__ __launch_bounds__(256) void bond_head(const u16* hb, const float* bw2,
                                                 const float* bb2, float* out) {
  __shared__ u16 hbuf[128 * 136];
  const int tid = threadIdx.x;
  const int bm = blockIdx.x;
  const int srw = tid >> 1, sh = tid & 1;
  float s[4] = {0.f, 0.f, 0.f, 0.f};

  for (int t = 0; t < 4; ++t) {
#pragma unroll
    for (int it = 0; it < 8; ++it) {
      const int id = it * 256 + tid;
      const int row = id >> 4, c8 = (id & 15) * 8;
      short8 v = *(const short8*)(hb + (size_t)(bm * 128 + row) * 512 + t * 128 + c8);
      *(short8*)&hbuf[row * 136 + c8] = v;
    }
    __syncthreads();
    const u16* hrow = &hbuf[srw * 136 + sh * 64];
    for (int cc = 0; cc < 64; ++cc) {
      const float h = bf2f(hrow[cc]);
#pragma unroll
      for (int o = 0; o < 4; ++o)
        s[o] += h * bw2[(t * 128 + sh * 64 + cc) * 4 + o];
    }
    __syncthreads();
  }
#pragma unroll
  for (int o = 0; o < 4; ++o) s[o] += __shfl_xor(s[o], 1);
  if ((tid & 1) == 0) {
    const int m = bm * 128 + srw;
#pragma unroll
    for (int o = 0; o < 4; ++o)
      out[(size_t)m * 69 + 65 + o] = s[o] + bb2[o];
  }
}

// ---------------- weight transpose + fp32->bf16 conversion ----------------------
__global__ __launch_bounds__(256) void prep(
    const float* topo_w1, const float* atom_w1, const float* bond_w1,
    const float* rbond_w, const float* wbond_w, const float* atom_w2,
    const float* topo_b1, const float* atom_b1,
    u16* WbT, u16* RbT, u16* TAT, u16* BdT, u16* AT2, float* biasTA) {
  int id = blockIdx.x * 256 + threadIdx.x;
  if (id < 512 * 512) { int n = id >> 9, k = id & 511; WbT[id] = f2bf(wbond_w[k * 512 + n]); return; }
  id -= 512 * 512;
  if (id < 512 * 576) { int n = id / 576, k = id % 576; RbT[id] = f2bf(rbond_w[k * 512 + n]); return; }
  id -= 512 * 576;
  if (id < 1024 * 1152) {
    int n = id / 1152, k = id % 1152;
    TAT[id] = f2bf((n < 512) ? topo_w1[k * 512 + n] : atom_w1[k * 512 + (n - 512)]);
    return;
  }
  id -= 1024 * 1152;
  if (id < 512 * 1664) { int n = id / 1664, k = id % 1664; BdT[id] = f2bf(bond_w1[k * 512 + n]); return; }
  id -= 512 * 1664;
  if (id < 64 * 512) { int n = id >> 9, k = id & 511; AT2[id] = f2bf(atom_w2[k * 64 + n]); return; }
  id -= 64 * 512;
  if (id < 1024) { biasTA[id] = (id < 512) ? topo_b1[id] : atom_b1[id - 512]; }
}

extern "C" void kernel_launch(void* const* d_in, const int* in_sizes, int n_in,
                              void* d_out, int out_size, void* d_ws, size_t ws_size,
                              hipStream_t stream) {
  const float* src     = (const float*)d_in[0];
  const float* gvec    = (const float*)d_in[1];
  const float* xnode   = (const float*)d_in[2];
  const float* znode   = (const float*)d_in[3];
  const float* atom1h  = (const float*)d_in[4];
  const float* bond1h  = (const float*)d_in[5];
  const float* topo_w1 = (const float*)d_in[6];
  const float* topo_b1 = (const float*)d_in[7];
  const float* topo_w2 = (const float*)d_in[8];
  const float* topo_b2 = (const float*)d_in[9];
  const float* atom_w1 = (const float*)d_in[10];
  const float* atom_b1 = (const float*)d_in[11];
  const float* atom_w2 = (const float*)d_in[12];
  const float* atom_b2 = (const float*)d_in[13];
  const float* bond_w1 = (const float*)d_in[14];
  const float* bond_b1 = (const float*)d_in[15];
  const float* bond_w2 = (const float*)d_in[16];
  const float* bond_b2 = (const float*)d_in[17];
  const float* rbond_w = (const float*)d_in[18];
  const float* rbond_b = (const float*)d_in[19];
  const float* wbond_w = (const float*)d_in[20];
  const float* wbond_b = (const float*)d_in[21];
  const int* bidx      = (const int*)d_in[22];

  char* ws = (char*)d_ws;
  u16*  WbT    = (u16*)(ws + 0);          // 512x512 bf16
  u16*  RbT    = (u16*)(ws + 524288);     // 512x576
  u16*  TAT    = (u16*)(ws + 1114112);    // 1024x1152
  u16*  BdT    = (u16*)(ws + 3473408);    // 512x1664
  u16*  AT2    = (u16*)(ws + 5177344);    // 64x512
  float* biasTA= (float*)(ws + 5242880);  // [1024] fp32  (end 5246976)
  u16*  gvecB  = (u16*)(ws + 5246976);    // M x 512 bf16 (end 38801408)
  u16*  xnodeB = (u16*)(ws + 38801408);   // M x 512      (end 72355840)
  u16*  ctxB   = (u16*)(ws + 72355840);   // M x 128      (end 80744448)
  u16*  a1hB   = (u16*)(ws + 80744448);   // M x 64       (end 84938752)
  u16*  znodeB = (u16*)(ws + 84938752);   // M x 512      (end 118493184)
  u16*  hist   = (u16*)(ws + 118493184);  // M x 512      (end 152047616)
  u16*  cur    = (u16*)(ws + 152047616);  // M x 512      (end 185602048)
  u16*  hb     = hist;                    // alias: hist dead after g2
  u16*  h1     = znodeB;                  // alias 64MB over znodeB+hist:
                                          // both dead once bond_gemm+bond_head done

  prep<<<dim3(10244), dim3(256), 0, stream>>>(
      topo_w1, atom_w1, bond_w1, rbond_w, wbond_w, atom_w2, topo_b1, atom_b1,
      WbT, RbT, TAT, BdT, AT2, biasTA);

  pack<<<dim3(27648), dim3(256), 0, stream>>>(
      gvec, xnode, znode, src, atom1h, bidx,
      gvecB, xnodeB, znodeB, ctxB, a1hB);

  // g1: hist = relu(znode @ wbond_w[:512] + bond1h @ wbond_w[512:] + b)
  GArgs g1 = {};
  g1.seg[0] = {znodeB, 512, 0}; g1.nseg = 1;
  g1.bt = WbT; g1.biasf = wbond_b; g1.out = hist; g1.K = 512; g1.N = 512;
  g1.tail_w = wbond_w + 512 * 512; g1.tail_x = bond1h;
  gemm_ms<<<dim3(4, 256), dim3(256), 0, stream>>>(g1);

  // g2: cur = relu([hist ; atom1h] @ rbond_w + b)
  GArgs g2 = {};
  g2.seg[0] = {hist, 512, 0}; g2.seg[1] = {a1hB, 64, 512}; g2.nseg = 2;
  g2.bt = RbT; g2.biasf = rbond_b; g2.out = cur; g2.K = 576; g2.N = 512;
  gemm_ms<<<dim3(4, 256), dim3(256), 0, stream>>>(g2);

  // bond layer-1: hb = relu([gvec ; cur ; znode ; ctx] @ bond_w1 + b1)
  GArgs gb = {};
  gb.seg[0] = {gvecB, 512, 0}; gb.seg[1] = {cur, 512, 512};
  gb.seg[2] = {znodeB, 512, 1024}; gb.seg[3] = {ctxB, 128, 1536}; gb.nseg = 4;
  gb.bt = BdT; gb.biasf = bond_b1; gb.out = hb; gb.K = 1664; gb.N = 512;
  gemm_ms<<<dim3(4, 256), dim3(256), 0, stream>>>(gb);

  // bond head (must finish before h1 overwrites hb region)
  bond_head<<<dim3(256), dim3(256), 0, stream>>>(hb, bond_w2, bond_b2, (float*)d_out);

  // ta layer-1: h1 = relu([gvec ; xnode ; ctx] @ [topo_w1|atom_w1] + bias)
  GArgs gt = {};
  gt.seg[0] = {gvecB, 512, 0}; gt.seg[1] = {xnodeB, 512, 512};
  gt.seg[2] = {ctxB, 128, 1024}; gt.nseg = 3;
  gt.bt = TAT; gt.biasf = biasTA; gt.out = h1; gt.K = 1152; gt.N = 1024;
  gemm_ms<<<dim3(8, 256), dim3(256), 0, stream>>>(gt);

  // topo + atom heads
  THArgs th = {h1, topo_w2, topo_b2, AT2, atom_b2, (float*)d_out};
  ta_heads<<<dim3(2, 256), dim3(256), 0, stream>>>(th);
}

// Round 3
// 658.895 us; speedup vs baseline: 1.2005x; 1.0179x over previous
//
#include <hip/hip_runtime.h>

typedef unsigned short u16;
typedef unsigned int u32;
typedef __attribute__((ext_vector_type(8))) short short8;
typedef __attribute__((ext_vector_type(4))) float f32x4;

#define M_ROWS 32768

__device__ __forceinline__ float bf2f(u16 u) {
  u32 x = ((u32)u) << 16;
  return __builtin_bit_cast(float, x);
}
__device__ __forceinline__ u16 f2bf(float f) {
  u32 x = __builtin_bit_cast(u32, f);
  x += 0x7fffu + ((x >> 16) & 1u);
  return (u16)(x >> 16);
}
// load 8 fp32 from p, RNE-round to one short8
__device__ __forceinline__ short8 ld8f(const float* p) {
  f32x4 x0 = *(const f32x4*)p;
  f32x4 x1 = *(const f32x4*)(p + 4);
  short8 s;
#pragma unroll
  for (int i = 0; i < 4; ++i) { s[i] = (short)f2bf(x0[i]); s[4 + i] = (short)f2bf(x1[i]); }
  return s;
}

// async global->LDS, 16B per lane, LDS dest = wave-uniform base + lane*16
__device__ __forceinline__ void lds16(u16* l, const u16* g) {
  __builtin_amdgcn_global_load_lds(
      (const __attribute__((address_space(1))) void*)g,
      (__attribute__((address_space(3))) void*)l, 16, 0, 0);
}

// ---------------- input pack: fp32 -> bf16 (+ ctx gather) -----------------------
__global__ __launch_bounds__(256) void pack(
    const float* gvec, const float* xnode, const float* znode,
    const float* src, const float* atom1h, const int* bidx,
    u16* gvecB, u16* xnodeB, u16* znodeB, u16* ctxB, u16* a1hB) {
  int id = blockIdx.x * 256 + threadIdx.x;  // one short8 chunk each
  const int NG = M_ROWS * 512 / 8;          // 2097152
  if (id < NG) { ((short8*)gvecB)[id] = ld8f(gvec + (size_t)id * 8); return; }
  id -= NG;
  if (id < NG) { ((short8*)xnodeB)[id] = ld8f(xnode + (size_t)id * 8); return; }
  id -= NG;
  if (id < NG) { ((short8*)znodeB)[id] = ld8f(znode + (size_t)id * 8); return; }
  id -= NG;
  const int NC = M_ROWS * 128 / 8;          // 524288
  if (id < NC) {
    const int m = id >> 4, c8 = (id & 15) * 8;
    ((short8*)ctxB)[id] = ld8f(src + (size_t)bidx[m] * 128 + c8);
    return;
  }
  id -= NC;
  const int NA = M_ROWS * 64 / 8;           // 262144
  if (id < NA) { ((short8*)a1hB)[id] = ld8f(atom1h + (size_t)id * 8); return; }
}

// ---------------- unified layer-1 GEMM: 128x128 tile, up to 4 A-segments --------
// out = relu(A @ B^T + bias [+ tail rank-4])  in bf16
struct SegB { const u16* ptr; int ld; int kstart; };
struct GArgs {
  SegB seg[4];
  int nseg;
  const u16* bt;       // B^T [N][K] bf16
  const float* biasf;  // [N] fp32
  u16* out;            // [M][N] relu'd bf16
  int K;
  int N;
  const float* tail_w; // fp32 wbond_w rows 512..515 (ld 512) or null
  const float* tail_x; // fp32 bond_onehot [M][4] or null
};

__global__ __launch_bounds__(256) void gemm_ms(GArgs a) {
  __shared__ u16 As[4096];
  __shared__ u16 Bs[4096];
  const int tid = threadIdx.x;
  // --- bijective XCD-chunked swizzle (all launches have nwg % 8 == 0) ---
  // HW dispatches orig round-robin over 8 XCDs; remap so each XCD owns a
  // contiguous chunk of logical tiles -> the n-tiles sharing an A-panel run
  // on ONE XCD and the panel is fetched from HBM once.
  const int nwg = gridDim.x * gridDim.y;
  const int orig = blockIdx.y * gridDim.x + blockIdx.x;
  const int cpx = nwg >> 3;
  const int swz = (orig & 7) * cpx + (orig >> 3);
  const int bn = swz % gridDim.x, bm = swz / gridDim.x;  // x = n-tile (fast)
  const int wave = tid >> 6, lane = tid & 63;
  const int wm = wave >> 1, wn = wave & 1;
  const int lm = lane & 15, lq = lane >> 4;
  const int ch0 = wave * 2;                  // this wave's two 16-row chunks
  const int srow = ch0 * 16 + (lane >> 2);   // staging row (chunk0)
  const int scol = (lane & 3) * 8;           // staging col (elements)
  const int gmA = bm * 128 + srow;
  const int gnB = bn * 128 + srow;
  u16* lA0 = As + ch0 * 512; u16* lA1 = lA0 + 512;
  u16* lB0 = Bs + ch0 * 512; u16* lB1 = lB0 + 512;
  const int K = a.K;
  const u16* pb = a.bt + (size_t)gnB * K + scol;

  f32x4 acc[4][4] = {};
  for (int kb = 0; kb < K; kb += 32) {
    int si = a.nseg - 1;
    while (si > 0 && kb < a.seg[si].kstart) --si;
    const u16* sp = a.seg[si].ptr;
    const int sld = a.seg[si].ld;
    const u16* pa = sp + (size_t)gmA * sld + (kb - a.seg[si].kstart) + scol;
    lds16(lB0, pb + kb);
    lds16(lB1, pb + kb + (size_t)16 * K);
    lds16(lA0, pa);
    lds16(lA1, pa + (size_t)16 * sld);
    __syncthreads();

    short8 af[4], bfr[4];
#pragma unroll
    for (int i = 0; i < 4; ++i)
      af[i] = *(const short8*)&As[(wm * 64 + i * 16 + lm) * 32 + lq * 8];
#pragma unroll
    for (int j = 0; j < 4; ++j)
      bfr[j] = *(const short8*)&Bs[(wn * 64 + j * 16 + lm) * 32 + lq * 8];
#pragma unroll
    for (int i = 0; i < 4; ++i)
#pragma unroll
      for (int j = 0; j < 4; ++j)
        acc[i][j] = __builtin_amdgcn_mfma_f32_16x16x32_bf16(af[i], bfr[j], acc[i][j], 0, 0, 0);
    __syncthreads();
  }

  const int gc0 = bn * 128 + wn * 64 + lm;
  float biasv[4], tw[4][4];
#pragma unroll
  for (int j = 0; j < 4; ++j) {
    const int gc = gc0 + j * 16;
    biasv[j] = a.biasf[gc];
    if (a.tail_w) {
#pragma unroll
      for (int k = 0; k < 4; ++k) tw[j][k] = a.tail_w[k * 512 + gc];
    }
  }
#pragma unroll
  for (int i = 0; i < 4; ++i) {
#pragma unroll
    for (int r = 0; r < 4; ++r) {
      const int gr = bm * 128 + wm * 64 + i * 16 + lq * 4 + r;
      float tx0 = 0.f, tx1 = 0.f, tx2 = 0.f, tx3 = 0.f;
      if (a.tail_w) {
        tx0 = a.tail_x[gr * 4 + 0];
        tx1 = a.tail_x[gr * 4 + 1];
        tx2 = a.tail_x[gr * 4 + 2];
        tx3 = a.tail_x[gr * 4 + 3];
      }
#pragma unroll
      for (int j = 0; j < 4; ++j) {
        float v = acc[i][j][r] + biasv[j];
        if (a.tail_w) v += tx0 * tw[j][0] + tx1 * tw[j][1] + tx2 * tw[j][2] + tx3 * tw[j][3];
        v = v > 0.f ? v : 0.f;
        a.out[(size_t)gr * a.N + gc0 + j * 16] = f2bf(v);
      }
    }
  }
}

// ---------------- topo + atom heads from materialized h1 [M][1024] --------------
struct THArgs {
  const u16* h1;      // [M][1024] relu'd bf16 (cols 0..511 topo, 512..1023 atom)
  const float* tw2;   // topo_w2 [512] fp32
  const float* tb2;   // topo_b2 [1]
  const u16* aw2t;    // AT2 [64][512] bf16
  const float* ab2;   // atom_b2 [64]
  float* out;         // [M][69] fp32
};

__global__ __launch_bounds__(256) void ta_heads(THArgs a) {
  __shared__ u16 hbuf[128 * 136];
  const int tid = threadIdx.x;
  const int half = blockIdx.x, bm = blockIdx.y;  // half: 0=topo, 1=atom
  const int wave = tid >> 6, lane = tid & 63;
  const int lm = lane & 15, lq = lane >> 4;

  float topo_acc = 0.f;
  f32x4 acc2[2][4] = {};

  for (int t = 0; t < 4; ++t) {
    // stage h1[bm*128 ..][half*512 + t*128 ..] -> hbuf[128][136] (padded)
#pragma unroll
    for (int it = 0; it < 8; ++it) {
      const int id = it * 256 + tid;
      const int row = id >> 4, c8 = (id & 15) * 8;
      short8 v = *(const short8*)(a.h1 + (size_t)(bm * 128 + row) * 1024 + half * 512 + t * 128 + c8);
      *(short8*)&hbuf[row * 136 + c8] = v;
    }
    __syncthreads();

    if (half == 0) {
      const int srw = tid >> 1, sh = tid & 1;
      const u16* hrow = &hbuf[srw * 136 + sh * 64];
      float s = 0.f;
      for (int cc = 0; cc < 64; ++cc)
        s += bf2f(hrow[cc]) * a.tw2[t * 128 + sh * 64 + cc];
      topo_acc += s;
    } else {
#pragma unroll
      for (int ks2 = 0; ks2 < 4; ++ks2) {
#pragma unroll
        for (int i2 = 0; i2 < 2; ++i2) {
          const short8 af2 = *(const short8*)&hbuf[(wave * 32 + i2 * 16 + lm) * 136 + ks2 * 32 + lq * 8];
#pragma unroll
          for (int j2 = 0; j2 < 4; ++j2) {
            const short8 bf2v = *(const short8*)&a.aw2t[(size_t)(j2 * 16 + lm) * 512 + t * 128 + ks2 * 32 + lq * 8];
            acc2[i2][j2] = __builtin_amdgcn_mfma_f32_16x16x32_bf16(af2, bf2v, acc2[i2][j2], 0, 0, 0);
          }
        }
      }
    }
    __syncthreads();
  }

  if (half == 0) {
    float s = topo_acc + __shfl_xor(topo_acc, 1);
    if ((tid & 1) == 0) {
      const int m = bm * 128 + (tid >> 1);
      a.out[(size_t)m * 69] = s + a.tb2[0];
    }
  } else {
#pragma unroll
    for (int i2 = 0; i2 < 2; ++i2)
#pragma unroll
      for (int j2 = 0; j2 < 4; ++j2)
#pragma unroll
        for (int r = 0; r < 4; ++r) {
          const int m = bm * 128 + wave * 32 + i2 * 16 + lq * 4 + r;
          const int o = j2 * 16 + lm;
          a.out[(size_t)m * 69 + 1 + o] = acc2[i2][j2][r] + a.ab2[o];
        }
  }
}

// ---------------- bond head from materialized hb [M][512] -----------------------
__global__ __launch_bounds__(256) void bond_head(const u16* hb, const float* bw2,
                                                 const float* bb2, float* out) {
  __shared__ u16 hbuf[128 * 136];
  const int tid = threadIdx.x;
  const int bm = blockIdx.x;
  const int srw = tid >> 1, sh = tid & 1;
  float s[4] = {0.f, 0.f, 0.f, 0.f};

  for (int t = 0; t < 4; ++t) {
#pragma unroll
    for (int it = 0; it < 8; ++it) {
      const int id = it * 256 + tid;
      const int row = id >> 4, c8 = (id & 15) * 8;
      short8 v = *(const short8*)(hb + (size_t)(bm * 128 + row) * 512 + t * 128 + c8);
      *(short8*)&hbuf[row * 136 + c8] = v;
    }
    __syncthreads();
    const u16* hrow = &hbuf[srw * 136 + sh * 64];
    for (int cc = 0; cc < 64; ++cc) {
      const float h = bf2f(hrow[cc]);
#pragma unroll
      for (int o = 0; o < 4; ++o)
        s[o] += h * bw2[(t * 128 + sh * 64 + cc) * 4 + o];
    }
    __syncthreads();
  }
#pragma unroll
  for (int o = 0; o < 4; ++o) s[o] += __shfl_xor(s[o], 1);
  if ((tid & 1) == 0) {
    const int m = bm * 128 + srw;
#pragma unroll
    for (int o = 0; o < 4; ++o)
      out[(size_t)m * 69 + 65 + o] = s[o] + bb2[o];
  }
}

// ---------------- weight transpose + fp32->bf16 conversion ----------------------
__global__ __launch_bounds__(256) void prep(
    const float* topo_w1, const float* atom_w1, const float* bond_w1,
    const float* rbond_w, const float* wbond_w, const float* atom_w2,
    const float* topo_b1, const float* atom_b1,
    u16* WbT, u16* RbT, u16* TAT, u16* BdT, u16* AT2, float* biasTA) {
  int id = blockIdx.x * 256 + threadIdx.x;
  if (id < 512 * 512) { int n = id >> 9, k = id & 511; WbT[id] = f2bf(wbond_w[k * 512 + n]); return; }
  id -= 512 * 512;
  if (id < 512 * 576) { int n = id / 576, k = id % 576; RbT[id] = f2bf(rbond_w[k * 512 + n]); return; }
  id -= 512 * 576;
  if (id < 1024 * 1152) {
    int n = id / 1152, k = id % 1152;
    TAT[id] = f2bf((n < 512) ? topo_w1[k * 512 + n] : atom_w1[k * 512 + (n - 512)]);
    return;
  }
  id -= 1024 * 1152;
  if (id < 512 * 1664) { int n = id / 1664, k = id % 1664; BdT[id] = f2bf(bond_w1[k * 512 + n]); return; }
  id -= 512 * 1664;
  if (id < 64 * 512) { int n = id >> 9, k = id & 511; AT2[id] = f2bf(atom_w2[k * 64 + n]); return; }
  id -= 64 * 512;
  if (id < 1024) { biasTA[id] = (id < 512) ? topo_b1[id] : atom_b1[id - 512]; }
}

extern "C" void kernel_launch(void* const* d_in, const int* in_sizes, int n_in,
                              void* d_out, int out_size, void* d_ws, size_t ws_size,
                              hipStream_t stream) {
  const float* src     = (const float*)d_in[0];
  const float* gvec    = (const float*)d_in[1];
  const float* xnode   = (const float*)d_in[2];
  const float* znode   = (const float*)d_in[3];
  const float* atom1h  = (const float*)d_in[4];
  const float* bond1h  = (const float*)d_in[5];
  const float* topo_w1 = (const float*)d_in[6];
  const float* topo_b1 = (const float*)d_in[7];
  const float* topo_w2 = (const float*)d_in[8];
  const float* topo_b2 = (const float*)d_in[9];
  const float* atom_w1 = (const float*)d_in[10];
  const float* atom_b1 = (const float*)d_in[11];
  const float* atom_w2 = (const float*)d_in[12];
  const float* atom_b2 = (const float*)d_in[13];
  const float* bond_w1 = (const float*)d_in[14];
  const float* bond_b1 = (const float*)d_in[15];
  const float* bond_w2 = (const float*)d_in[16];
  const float* bond_b2 = (const float*)d_in[17];
  const float* rbond_w = (const float*)d_in[18];
  const float* rbond_b = (const float*)d_in[19];
  const float* wbond_w = (const float*)d_in[20];
  const float* wbond_b = (const float*)d_in[21];
  const int* bidx      = (const int*)d_in[22];

  char* ws = (char*)d_ws;
  u16*  WbT    = (u16*)(ws + 0);          // 512x512 bf16
  u16*  RbT    = (u16*)(ws + 524288);     // 512x576
  u16*  TAT    = (u16*)(ws + 1114112);    // 1024x1152
  u16*  BdT    = (u16*)(ws + 3473408);    // 512x1664
  u16*  AT2    = (u16*)(ws + 5177344);    // 64x512
  float* biasTA= (float*)(ws + 5242880);  // [1024] fp32  (end 5246976)
  u16*  gvecB  = (u16*)(ws + 5246976);    // M x 512 bf16 (end 38801408)
  u16*  xnodeB = (u16*)(ws + 38801408);   // M x 512      (end 72355840)
  u16*  ctxB   = (u16*)(ws + 72355840);   // M x 128      (end 80744448)
  u16*  a1hB   = (u16*)(ws + 80744448);   // M x 64       (end 84938752)
  u16*  znodeB = (u16*)(ws + 84938752);   // M x 512      (end 118493184)
  u16*  hist   = (u16*)(ws + 118493184);  // M x 512      (end 152047616)
  u16*  cur    = (u16*)(ws + 152047616);  // M x 512      (end 185602048)
  u16*  hb     = hist;                    // alias: hist dead after g2
  u16*  h1     = znodeB;                  // alias 64MB over znodeB+hist:
                                          // both dead once bond_gemm+bond_head done

  prep<<<dim3(10244), dim3(256), 0, stream>>>(
      topo_w1, atom_w1, bond_w1, rbond_w, wbond_w, atom_w2, topo_b1, atom_b1,
      WbT, RbT, TAT, BdT, AT2, biasTA);

  pack<<<dim3(27648), dim3(256), 0, stream>>>(
      gvec, xnode, znode, src, atom1h, bidx,
      gvecB, xnodeB, znodeB, ctxB, a1hB);

  // g1: hist = relu(znode @ wbond_w[:512] + bond1h @ wbond_w[512:] + b)
  GArgs g1 = {};
  g1.seg[0] = {znodeB, 512, 0}; g1.nseg = 1;
  g1.bt = WbT; g1.biasf = wbond_b; g1.out = hist; g1.K = 512; g1.N = 512;
  g1.tail_w = wbond_w + 512 * 512; g1.tail_x = bond1h;
  gemm_ms<<<dim3(4, 256), dim3(256), 0, stream>>>(g1);

  // g2: cur = relu([hist ; atom1h] @ rbond_w + b)
  GArgs g2 = {};
  g2.seg[0] = {hist, 512, 0}; g2.seg[1] = {a1hB, 64, 512}; g2.nseg = 2;
  g2.bt = RbT; g2.biasf = rbond_b; g2.out = cur; g2.K = 576; g2.N = 512;
  gemm_ms<<<dim3(4, 256), dim3(256), 0, stream>>>(g2);

  // bond layer-1: hb = relu([gvec ; cur ; znode ; ctx] @ bond_w1 + b1)
  GArgs gb = {};
  gb.seg[0] = {gvecB, 512, 0}; gb.seg[1] = {cur, 512, 512};
  gb.seg[2] = {znodeB, 512, 1024}; gb.seg[3] = {ctxB, 128, 1536}; gb.nseg = 4;
  gb.bt = BdT; gb.biasf = bond_b1; gb.out = hb; gb.K = 1664; gb.N = 512;
  gemm_ms<<<dim3(4, 256), dim3(256), 0, stream>>>(gb);

  // bond head (must finish before h1 overwrites hb region)
  bond_head<<<dim3(256), dim3(256), 0, stream>>>(hb, bond_w2, bond_b2, (float*)d_out);

  // ta layer-1: h1 = relu([gvec ; xnode ; ctx] @ [topo_w1|atom_w1] + bias)
  GArgs gt = {};
  gt.seg[0] = {gvecB, 512, 0}; gt.seg[1] = {xnodeB, 512, 512};
  gt.seg[2] = {ctxB, 128, 1024}; gt.nseg = 3;
  gt.bt = TAT; gt.biasf = biasTA; gt.out = h1; gt.K = 1152; gt.N = 1024;
  gemm_ms<<<dim3(8, 256), dim3(256), 0, stream>>>(gt);

  // topo + atom heads
  THArgs th = {h1, topo_w2, topo_b2, AT2, atom_b2, (float*)d_out};
  ta_heads<<<dim3(2, 256), dim3(256), 0, stream>>>(th);
}

// Round 4
// 581.121 us; speedup vs baseline: 1.3611x; 1.1338x over previous
//
#include <hip/hip_runtime.h>

typedef unsigned short u16;
typedef unsigned int u32;
typedef __attribute__((ext_vector_type(8))) short short8;
typedef __attribute__((ext_vector_type(4))) float f32x4;

#define M_ROWS 32768
#define MFMA16 __builtin_amdgcn_mfma_f32_16x16x32_bf16

__device__ __forceinline__ float bf2f(u16 u) {
  u32 x = ((u32)u) << 16;
  return __builtin_bit_cast(float, x);
}
__device__ __forceinline__ u16 f2bf(float f) {
  u32 x = __builtin_bit_cast(u32, f);
  x += 0x7fffu + ((x >> 16) & 1u);
  return (u16)(x >> 16);
}
// load 8 fp32 from p, RNE-round to one short8
__device__ __forceinline__ short8 ld8f(const float* p) {
  f32x4 x0 = *(const f32x4*)p;
  f32x4 x1 = *(const f32x4*)(p + 4);
  short8 s;
#pragma unroll
  for (int i = 0; i < 4; ++i) { s[i] = (short)f2bf(x0[i]); s[4 + i] = (short)f2bf(x1[i]); }
  return s;
}

// async global->LDS, 16B per lane, LDS dest = wave-uniform base + lane*16
__device__ __forceinline__ void lds16(u16* l, const u16* g) {
  __builtin_amdgcn_global_load_lds(
      (const __attribute__((address_space(1))) void*)g,
      (__attribute__((address_space(3))) void*)l, 16, 0, 0);
}

// ---------------- input pack: fp32 -> bf16 (+ ctx gather) -----------------------
__global__ __launch_bounds__(256) void pack(
    const float* gvec, const float* xnode, const float* znode,
    const float* src, const float* atom1h, const int* bidx,
    u16* gvecB, u16* xnodeB, u16* znodeB, u16* ctxB, u16* a1hB) {
  int id = blockIdx.x * 256 + threadIdx.x;  // one short8 chunk each
  const int NG = M_ROWS * 512 / 8;          // 2097152
  if (id < NG) { ((short8*)gvecB)[id] = ld8f(gvec + (size_t)id * 8); return; }
  id -= NG;
  if (id < NG) { ((short8*)xnodeB)[id] = ld8f(xnode + (size_t)id * 8); return; }
  id -= NG;
  if (id < NG) { ((short8*)znodeB)[id] = ld8f(znode + (size_t)id * 8); return; }
  id -= NG;
  const int NC = M_ROWS * 128 / 8;          // 524288
  if (id < NC) {
    const int m = id >> 4, c8 = (id & 15) * 8;
    ((short8*)ctxB)[id] = ld8f(src + (size_t)bidx[m] * 128 + c8);
    return;
  }
  id -= NC;
  const int NA = M_ROWS * 64 / 8;           // 262144
  if (id < NA) { ((short8*)a1hB)[id] = ld8f(atom1h + (size_t)id * 8); return; }
}

// ---------------- 256x256 pipelined GEMM (T2+T3+T4+T5), up to 4 A-segments ------
// out = relu(A @ B^T + bias [+ tail rank-4]) in bf16
struct SegB { const u16* ptr; int ld; int kstart; };
struct GArgs {
  SegB seg[4];
  int nseg;
  const u16* bt;       // B^T [N][K] bf16
  const float* biasf;  // [N] fp32
  u16* out;            // [M][N] relu'd bf16
  int K;
  int N;
  const float* tail_w; // fp32 wbond_w rows 512..515 (ld 512) or null
  const float* tail_x; // fp32 bond_onehot [M][4] or null
};

__global__ __launch_bounds__(512) void gemm256(GArgs a) {
  // double-buffered 256x64 tiles, row-major 64-col rows, XOR-swizzled content
  __shared__ __align__(16) u16 Ab[2][256 * 64];
  __shared__ __align__(16) u16 Bb[2][256 * 64];
  const int tid = threadIdx.x;
  // bijective XCD-chunked swizzle (nwg % 8 == 0 in all launches)
  const int nwg = gridDim.x * gridDim.y;
  const int orig = blockIdx.y * gridDim.x + blockIdx.x;
  const int swz = (orig & 7) * (nwg >> 3) + (orig >> 3);
  const int bn = swz % gridDim.x, bm = swz / gridDim.x;
  const int wave = tid >> 6, lane = tid & 63;
  const int wm = wave >> 2, wn = wave & 3;   // 2M x 4N wave grid
  const int lm = lane & 15, lq = lane >> 4;
  const int srow = tid >> 3;                 // staging row 0..63 per round
  const int scol = ((tid & 7) ^ (srow & 7)) * 8;  // pre-swizzled source col
  const int rA0 = wm * 128 + lm;             // A frag base row
  const int rB0 = wn * 64 + lm;              // B frag base row
  const int cx0 = (lq ^ (lm & 7)) * 8;       // swizzled col, k-slice 0
  const int cx1 = ((4 + lq) ^ (lm & 7)) * 8; // swizzled col, k-slice 1
  const int K = a.K;
  const u16* bpan = a.bt + (size_t)(bn * 256) * K;
  f32x4 acc[8][4] = {};

  // prologue: stage tile 0 into buf 0 (A: 4 rounds, B: 4 rounds)
  {
    const int ld0 = a.seg[0].ld;
    const u16* ap0 = a.seg[0].ptr + (size_t)(bm * 256) * ld0;
#pragma unroll
    for (int h = 0; h < 4; ++h)
      lds16(&Ab[0][h * 4096] + tid * 8, ap0 + (size_t)(h * 64 + srow) * ld0 + scol);
#pragma unroll
    for (int h = 0; h < 4; ++h)
      lds16(&Bb[0][h * 4096] + tid * 8, bpan + (size_t)(h * 64 + srow) * K + scol);
    asm volatile("s_waitcnt vmcnt(0)" ::: "memory");
    __builtin_amdgcn_s_barrier();
    __builtin_amdgcn_sched_barrier(0);
  }

  const int nt = K >> 6;
  for (int kt = 0; kt < nt; ++kt) {
    const int p = kt & 1;
    const u16* Ar = &Ab[p][0];
    const u16* Br = &Bb[p][0];
    u16* Aw = &Ab[p ^ 1][0];
    u16* Bw = &Bb[p ^ 1][0];
    const bool pf = (kt + 1 < nt);
    const u16* apN = nullptr; const u16* bpN = nullptr; int aldN = 0;
    if (pf) {
      const int kb2 = (kt + 1) << 6;
      int si = a.nseg - 1;
      while (si > 0 && kb2 < a.seg[si].kstart) --si;
      aldN = a.seg[si].ld;
      apN = a.seg[si].ptr + (size_t)(bm * 256) * aldN + (kb2 - a.seg[si].kstart);
      bpN = bpan + kb2;
    }
    short8 aLo[4][2], aHi[4][2], bLo[2][2], bHi[2][2], bLo2[2][2];

    // ---- phase 0: stage next A-half0 | read A-lo,B-lo | MFMA quad(0,0) ----
    if (pf) {
      lds16(Aw + tid * 8, apN + (size_t)srow * aldN + scol);
      lds16(Aw + 4096 + tid * 8, apN + (size_t)(64 + srow) * aldN + scol);
    }
#pragma unroll
    for (int m = 0; m < 4; ++m) {
      aLo[m][0] = *(const short8*)&Ar[(rA0 + m * 16) * 64 + cx0];
      aLo[m][1] = *(const short8*)&Ar[(rA0 + m * 16) * 64 + cx1];
    }
#pragma unroll
    for (int n = 0; n < 2; ++n) {
      bLo[n][0] = *(const short8*)&Br[(rB0 + n * 16) * 64 + cx0];
      bLo[n][1] = *(const short8*)&Br[(rB0 + n * 16) * 64 + cx1];
    }
    __builtin_amdgcn_s_setprio(1);
#pragma unroll
    for (int m = 0; m < 4; ++m)
#pragma unroll
      for (int n = 0; n < 2; ++n)
#pragma unroll
        for (int ks = 0; ks < 2; ++ks)
          acc[m][n] = MFMA16(aLo[m][ks], bLo[n][ks], acc[m][n], 0, 0, 0);
    __builtin_amdgcn_s_setprio(0);

    // ---- phase 1: stage next A-half1 | read B-hi | MFMA quad(0,1) ----
    if (pf) {
      lds16(Aw + 8192 + tid * 8, apN + (size_t)(128 + srow) * aldN + scol);
      lds16(Aw + 12288 + tid * 8, apN + (size_t)(192 + srow) * aldN + scol);
    }
#pragma unroll
    for (int n = 0; n < 2; ++n) {
      bHi[n][0] = *(const short8*)&Br[(rB0 + 32 + n * 16) * 64 + cx0];
      bHi[n][1] = *(const short8*)&Br[(rB0 + 32 + n * 16) * 64 + cx1];
    }
    __builtin_amdgcn_s_setprio(1);
#pragma unroll
    for (int m = 0; m < 4; ++m)
#pragma unroll
      for (int n = 0; n < 2; ++n)
#pragma unroll
        for (int ks = 0; ks < 2; ++ks)
          acc[m][2 + n] = MFMA16(aLo[m][ks], bHi[n][ks], acc[m][2 + n], 0, 0, 0);
    __builtin_amdgcn_s_setprio(0);

    // ---- phase 2: stage next B-half0 | read A-hi | MFMA quad(1,1) ----
    if (pf) {
      lds16(Bw + tid * 8, bpN + (size_t)srow * K + scol);
      lds16(Bw + 4096 + tid * 8, bpN + (size_t)(64 + srow) * K + scol);
    }
#pragma unroll
    for (int m = 0; m < 4; ++m) {
      aHi[m][0] = *(const short8*)&Ar[(rA0 + 64 + m * 16) * 64 + cx0];
      aHi[m][1] = *(const short8*)&Ar[(rA0 + 64 + m * 16) * 64 + cx1];
    }
    __builtin_amdgcn_s_setprio(1);
#pragma unroll
    for (int m = 0; m < 4; ++m)
#pragma unroll
      for (int n = 0; n < 2; ++n)
#pragma unroll
        for (int ks = 0; ks < 2; ++ks)
          acc[4 + m][2 + n] = MFMA16(aHi[m][ks], bHi[n][ks], acc[4 + m][2 + n], 0, 0, 0);
    __builtin_amdgcn_s_setprio(0);

    // ---- phase 3: stage next B-half1 | re-read B-lo | MFMA quad(1,0) ----
    if (pf) {
      lds16(Bw + 8192 + tid * 8, bpN + (size_t)(128 + srow) * K + scol);
      lds16(Bw + 12288 + tid * 8, bpN + (size_t)(192 + srow) * K + scol);
    }
#pragma unroll
    for (int n = 0; n < 2; ++n) {
      bLo2[n][0] = *(const short8*)&Br[(rB0 + n * 16) * 64 + cx0];
      bLo2[n][1] = *(const short8*)&Br[(rB0 + n * 16) * 64 + cx1];
    }
    __builtin_amdgcn_s_setprio(1);
#pragma unroll
    for (int m = 0; m < 4; ++m)
#pragma unroll
      for (int n = 0; n < 2; ++n)
#pragma unroll
        for (int ks = 0; ks < 2; ++ks)
          acc[4 + m][n] = MFMA16(aHi[m][ks], bLo2[n][ks], acc[4 + m][n], 0, 0, 0);
    __builtin_amdgcn_s_setprio(0);

    // ---- tile boundary: counted wait (next tile's 8 loads) + single barrier ----
    if (pf) {
      asm volatile("s_waitcnt vmcnt(0)" ::: "memory");
      __builtin_amdgcn_s_barrier();
      __builtin_amdgcn_sched_barrier(0);
    }
  }

  // ---- epilogue: bias [+rank-4 tail] + relu + bf16 store ----
  const int gc0 = bn * 256 + wn * 64 + lm;
  float biasv[4], tw[4][4];
#pragma unroll
  for (int j = 0; j < 4; ++j) {
    biasv[j] = a.biasf[gc0 + j * 16];
    if (a.tail_w) {
#pragma unroll
      for (int o = 0; o < 4; ++o) tw[j][o] = a.tail_w[o * 512 + gc0 + j * 16];
    }
  }
#pragma unroll
  for (int i = 0; i < 8; ++i) {
#pragma unroll
    for (int r = 0; r < 4; ++r) {
      const int gr = bm * 256 + wm * 128 + i * 16 + lq * 4 + r;
      float tx0 = 0.f, tx1 = 0.f, tx2 = 0.f, tx3 = 0.f;
      if (a.tail_w) {
        f32x4 t = *(const f32x4*)&a.tail_x[gr * 4];
        tx0 = t[0]; tx1 = t[1]; tx2 = t[2]; tx3 = t[3];
      }
#pragma unroll
      for (int j = 0; j < 4; ++j) {
        float v = acc[i][j][r] + biasv[j];
        if (a.tail_w) v += tx0 * tw[j][0] + tx1 * tw[j][1] + tx2 * tw[j][2] + tx3 * tw[j][3];
        v = v > 0.f ? v : 0.f;
        a.out[(size_t)gr * a.N + gc0 + j * 16] = f2bf(v);
      }
    }
  }
}

// ---------------- topo + atom heads from materialized h1 [M][1024] --------------
struct THArgs {
  const u16* h1;      // [M][1024] relu'd bf16 (cols 0..511 topo, 512..1023 atom)
  const float* tw2;   // topo_w2 [512] fp32
  const float* tb2;   // topo_b2 [1]
  const u16* aw2t;    // AT2 [64][512] bf16
  const float* ab2;   // atom_b2 [64]
  float* out;         // [M][69] fp32
};

__global__ __launch_bounds__(256) void ta_heads(THArgs a) {
  __shared__ u16 hbuf[128 * 136];
  const int tid = threadIdx.x;
  const int half = blockIdx.x, bm = blockIdx.y;  // half: 0=topo, 1=atom
  const int wave = tid >> 6, lane = tid & 63;
  const int lm = lane & 15, lq = lane >> 4;

  float topo_acc = 0.f;
  f32x4 acc2[2][4] = {};

  for (int t = 0; t < 4; ++t) {
    // stage h1[bm*128 ..][half*512 + t*128 ..] -> hbuf[128][136] (padded)
#pragma unroll
    for (int it = 0; it < 8; ++it) {
      const int id = it * 256 + tid;
      const int row = id >> 4, c8 = (id & 15) * 8;
      short8 v = *(const short8*)(a.h1 + (size_t)(bm * 128 + row) * 1024 + half * 512 + t * 128 + c8);
      *(short8*)&hbuf[row * 136 + c8] = v;
    }
    __syncthreads();

    if (half == 0) {
      const int srw = tid >> 1, sh = tid & 1;
      const u16* hrow = &hbuf[srw * 136 + sh * 64];
      float s = 0.f;
      for (int cc = 0; cc < 64; ++cc)
        s += bf2f(hrow[cc]) * a.tw2[t * 128 + sh * 64 + cc];
      topo_acc += s;
    } else {
#pragma unroll
      for (int ks2 = 0; ks2 < 4; ++ks2) {
#pragma unroll
        for (int i2 = 0; i2 < 2; ++i2) {
          const short8 af2 = *(const short8*)&hbuf[(wave * 32 + i2 * 16 + lm) * 136 + ks2 * 32 + lq * 8];
#pragma unroll
          for (int j2 = 0; j2 < 4; ++j2) {
            const short8 bf2v = *(const short8*)&a.aw2t[(size_t)(j2 * 16 + lm) * 512 + t * 128 + ks2 * 32 + lq * 8];
            acc2[i2][j2] = MFMA16(af2, bf2v, acc2[i2][j2], 0, 0, 0);
          }
        }
      }
    }
    __syncthreads();
  }

  if (half == 0) {
    float s = topo_acc + __shfl_xor(topo_acc, 1);
    if ((tid & 1) == 0) {
      const int m = bm * 128 + (tid >> 1);
      a.out[(size_t)m * 69] = s + a.tb2[0];
    }
  } else {
#pragma unroll
    for (int i2 = 0; i2 < 2; ++i2)
#pragma unroll
      for (int j2 = 0; j2 < 4; ++j2)
#pragma unroll
        for (int r = 0; r < 4; ++r) {
          const int m = bm * 128 + wave * 32 + i2 * 16 + lq * 4 + r;
          const int o = j2 * 16 + lm;
          a.out[(size_t)m * 69 + 1 + o] = acc2[i2][j2][r] + a.ab2[o];
        }
  }
}

// ---------------- bond head from materialized hb [M][512] -----------------------
__global__ __launch_bounds__(256) void bond_head(const u16* hb, const float* bw2,
                                                 const float* bb2, float* out) {
  __shared__ u16 hbuf[128 * 136];
  const int tid = threadIdx.x;
  const int bm = blockIdx.x;
  const int srw = tid >> 1, sh = tid & 1;
  float s[4] = {0.f, 0.f, 0.f, 0.f};

  for (int t = 0; t < 4; ++t) {
#pragma unroll
    for (int it = 0; it < 8; ++it) {
      const int id = it * 256 + tid;
      const int row = id >> 4, c8 = (id & 15) * 8;
      short8 v = *(const short8*)(hb + (size_t)(bm * 128 + row) * 512 + t * 128 + c8);
      *(short8*)&hbuf[row * 136 + c8] = v;
    }
    __syncthreads();
    const u16* hrow = &hbuf[srw * 136 + sh * 64];
    for (int cc = 0; cc < 64; ++cc) {
      const float h = bf2f(hrow[cc]);
#pragma unroll
      for (int o = 0; o < 4; ++o)
        s[o] += h * bw2[(t * 128 + sh * 64 + cc) * 4 + o];
    }
    __syncthreads();
  }
#pragma unroll
  for (int o = 0; o < 4; ++o) s[o] += __shfl_xor(s[o], 1);
  if ((tid & 1) == 0) {
    const int m = bm * 128 + srw;
#pragma unroll
    for (int o = 0; o < 4; ++o)
      out[(size_t)m * 69 + 65 + o] = s[o] + bb2[o];
  }
}

// ---------------- weight transpose + fp32->bf16 conversion ----------------------
__global__ __launch_bounds__(256) void prep(
    const float* topo_w1, const float* atom_w1, const float* bond_w1,
    const float* rbond_w, const float* wbond_w, const float* atom_w2,
    const float* topo_b1, const float* atom_b1,
    u16* WbT, u16* RbT, u16* TAT, u16* BdT, u16* AT2, float* biasTA) {
  int id = blockIdx.x * 256 + threadIdx.x;
  if (id < 512 * 512) { int n = id >> 9, k = id & 511; WbT[id] = f2bf(wbond_w[k * 512 + n]); return; }
  id -= 512 * 512;
  if (id < 512 * 576) { int n = id / 576, k = id % 576; RbT[id] = f2bf(rbond_w[k * 512 + n]); return; }
  id -= 512 * 576;
  if (id < 1024 * 1152) {
    int n = id / 1152, k = id % 1152;
    TAT[id] = f2bf((n < 512) ? topo_w1[k * 512 + n] : atom_w1[k * 512 + (n - 512)]);
    return;
  }
  id -= 1024 * 1152;
  if (id < 512 * 1664) { int n = id / 1664, k = id % 1664; BdT[id] = f2bf(bond_w1[k * 512 + n]); return; }
  id -= 512 * 1664;
  if (id < 64 * 512) { int n = id >> 9, k = id & 511; AT2[id] = f2bf(atom_w2[k * 64 + n]); return; }
  id -= 64 * 512;
  if (id < 1024) { biasTA[id] = (id < 512) ? topo_b1[id] : atom_b1[id - 512]; }
}

extern "C" void kernel_launch(void* const* d_in, const int* in_sizes, int n_in,
                              void* d_out, int out_size, void* d_ws, size_t ws_size,
                              hipStream_t stream) {
  const float* src     = (const float*)d_in[0];
  const float* gvec    = (const float*)d_in[1];
  const float* xnode   = (const float*)d_in[2];
  const float* znode   = (const float*)d_in[3];
  const float* atom1h  = (const float*)d_in[4];
  const float* bond1h  = (const float*)d_in[5];
  const float* topo_w1 = (const float*)d_in[6];
  const float* topo_b1 = (const float*)d_in[7];
  const float* topo_w2 = (const float*)d_in[8];
  const float* topo_b2 = (const float*)d_in[9];
  const float* atom_w1 = (const float*)d_in[10];
  const float* atom_b1 = (const float*)d_in[11];
  const float* atom_w2 = (const float*)d_in[12];
  const float* atom_b2 = (const float*)d_in[13];
  const float* bond_w1 = (const float*)d_in[14];
  const float* bond_b1 = (const float*)d_in[15];
  const float* bond_w2 = (const float*)d_in[16];
  const float* bond_b2 = (const float*)d_in[17];
  const float* rbond_w = (const float*)d_in[18];
  const float* rbond_b = (const float*)d_in[19];
  const float* wbond_w = (const float*)d_in[20];
  const float* wbond_b = (const float*)d_in[21];
  const int* bidx      = (const int*)d_in[22];

  char* ws = (char*)d_ws;
  u16*  WbT    = (u16*)(ws + 0);          // 512x512 bf16
  u16*  RbT    = (u16*)(ws + 524288);     // 512x576
  u16*  TAT    = (u16*)(ws + 1114112);    // 1024x1152
  u16*  BdT    = (u16*)(ws + 3473408);    // 512x1664
  u16*  AT2    = (u16*)(ws + 5177344);    // 64x512
  float* biasTA= (float*)(ws + 5242880);  // [1024] fp32  (end 5246976)
  u16*  gvecB  = (u16*)(ws + 5246976);    // M x 512 bf16 (end 38801408)
  u16*  xnodeB = (u16*)(ws + 38801408);   // M x 512      (end 72355840)
  u16*  ctxB   = (u16*)(ws + 72355840);   // M x 128      (end 80744448)
  u16*  a1hB   = (u16*)(ws + 80744448);   // M x 64       (end 84938752)
  u16*  znodeB = (u16*)(ws + 84938752);   // M x 512      (end 118493184)
  u16*  hist   = (u16*)(ws + 118493184);  // M x 512      (end 152047616)
  u16*  cur    = (u16*)(ws + 152047616);  // M x 512      (end 185602048)
  u16*  hb     = hist;                    // alias: hist dead after g2
  u16*  h1     = znodeB;                  // alias 64MB over znodeB+hist:
                                          // both dead once bond_gemm+bond_head done

  prep<<<dim3(10244), dim3(256), 0, stream>>>(
      topo_w1, atom_w1, bond_w1, rbond_w, wbond_w, atom_w2, topo_b1, atom_b1,
      WbT, RbT, TAT, BdT, AT2, biasTA);

  pack<<<dim3(27648), dim3(256), 0, stream>>>(
      gvec, xnode, znode, src, atom1h, bidx,
      gvecB, xnodeB, znodeB, ctxB, a1hB);

  // g1: hist = relu(znode @ wbond_w[:512] + bond1h @ wbond_w[512:] + b)
  GArgs g1 = {};
  g1.seg[0] = {znodeB, 512, 0}; g1.nseg = 1;
  g1.bt = WbT; g1.biasf = wbond_b; g1.out = hist; g1.K = 512; g1.N = 512;
  g1.tail_w = wbond_w + 512 * 512; g1.tail_x = bond1h;
  gemm256<<<dim3(2, 128), dim3(512), 0, stream>>>(g1);

  // g2: cur = relu([hist ; atom1h] @ rbond_w + b)
  GArgs g2 = {};
  g2.seg[0] = {hist, 512, 0}; g2.seg[1] = {a1hB, 64, 512}; g2.nseg = 2;
  g2.bt = RbT; g2.biasf = rbond_b; g2.out = cur; g2.K = 576; g2.N = 512;
  gemm256<<<dim3(2, 128), dim3(512), 0, stream>>>(g2);

  // bond layer-1: hb = relu([gvec ; cur ; znode ; ctx] @ bond_w1 + b1)
  GArgs gb = {};
  gb.seg[0] = {gvecB, 512, 0}; gb.seg[1] = {cur, 512, 512};
  gb.seg[2] = {znodeB, 512, 1024}; gb.seg[3] = {ctxB, 128, 1536}; gb.nseg = 4;
  gb.bt = BdT; gb.biasf = bond_b1; gb.out = hb; gb.K = 1664; gb.N = 512;
  gemm256<<<dim3(2, 128), dim3(512), 0, stream>>>(gb);

  // bond head (must finish before h1 overwrites hb region)
  bond_head<<<dim3(256), dim3(256), 0, stream>>>(hb, bond_w2, bond_b2, (float*)d_out);

  // ta layer-1: h1 = relu([gvec ; xnode ; ctx] @ [topo_w1|atom_w1] + bias)
  GArgs gt = {};
  gt.seg[0] = {gvecB, 512, 0}; gt.seg[1] = {xnodeB, 512, 512};
  gt.seg[2] = {ctxB, 128, 1024}; gt.nseg = 3;
  gt.bt = TAT; gt.biasf = biasTA; gt.out = h1; gt.K = 1152; gt.N = 1024;
  gemm256<<<dim3(4, 128), dim3(512), 0, stream>>>(gt);

  // topo + atom heads
  THArgs th = {h1, topo_w2, topo_b2, AT2, atom_b2, (float*)d_out};
  ta_heads<<<dim3(2, 256), dim3(256), 0, stream>>>(th);
}